// Round 10
// baseline (119.811 us; speedup 1.0000x reference)
//
#include <hip/hip_runtime.h>
#include <hip/hip_bf16.h>

#define NREL 8
#define CH   64   // IN_CH == HID_CH == 64
#define NPB  16   // nodes per block in fused agg+gemm

typedef unsigned int uint32;
typedef __attribute__((ext_vector_type(8))) short bf16x8;
typedef __attribute__((ext_vector_type(4))) float f32x4;
union U4 { uint4 u; bf16x8 v; };

// ---- bf16 helpers (RNE) ----------------------------------------------------
static __device__ __forceinline__ uint32 packbf(float a, float b) {
    uint32 ua = __float_as_uint(a), ub = __float_as_uint(b);
    ua = (ua + 0x7fffu + ((ua >> 16) & 1u)) >> 16;          // low half  (elem 0 = even k)
    ub = (ub + 0x7fffu + ((ub >> 16) & 1u)) & 0xffff0000u;  // high half (elem 1 = odd k)
    return ua | ub;
}
static __device__ __forceinline__ float bflo(uint32 w) { return __uint_as_float(w << 16); }
static __device__ __forceinline__ float bfhi(uint32 w) { return __uint_as_float(w & 0xffff0000u); }

// ---------------------------------------------------------------------------
// prep: blocks [0,16) build B-fragments from W; the rest pack x into bf16.
// Bfrag[((ks*4+c)*64+lane)*4 + j2] = packed W[ks*32+(lane>>4)*8+2j2..+1][c*16+(lane&15)]
// (same lane->k mapping as the A side, so any k-permutation cancels).
// ---------------------------------------------------------------------------
__global__ __launch_bounds__(256) void prep_k(
    const float* __restrict__ x, uint32* __restrict__ xbf,
    const float* __restrict__ Wf, uint32* __restrict__ Bfrag, int n2)
{
    if (blockIdx.x < 16) {
        const int idx  = blockIdx.x * 256 + threadIdx.x;   // 0..4095
        const int lane = idx & 63;
        const int c    = (idx >> 6) & 3;
        const int ks   = idx >> 8;                          // 0..15
        const int col  = c * 16 + (lane & 15);
        const int k0   = ks * 32 + (lane >> 4) * 8;
        uint4 o;
        o.x = packbf(Wf[(k0 + 0) * 64 + col], Wf[(k0 + 1) * 64 + col]);
        o.y = packbf(Wf[(k0 + 2) * 64 + col], Wf[(k0 + 3) * 64 + col]);
        o.z = packbf(Wf[(k0 + 4) * 64 + col], Wf[(k0 + 5) * 64 + col]);
        o.w = packbf(Wf[(k0 + 6) * 64 + col], Wf[(k0 + 7) * 64 + col]);
        *(uint4*)(Bfrag + (size_t)idx * 4) = o;
    } else {
        const int i = (blockIdx.x - 16) * 256 + threadIdx.x;
        if (i < n2) {
            const float2 v = ((const float2*)x)[i];
            xbf[i] = packbf(v.x, v.y);
        }
    }
}

// ---------------------------------------------------------------------------
// Coarse histogram over c = dst>>8: per-block partials (no global atomics,
// no pre-zeroed buffer needed).
// ---------------------------------------------------------------------------
__global__ __launch_bounds__(256) void chist_k(
    const int* __restrict__ ei, int* __restrict__ cpart, int nE, int nT)
{
    __shared__ int h[256];
    h[threadIdx.x] = 0;
    __syncthreads();
    for (int e = blockIdx.x * 256 + threadIdx.x; e < nE; e += nT)
        atomicAdd(&h[ei[nE + e] >> 8], 1);
    __syncthreads();
    cpart[blockIdx.x * 256 + threadIdx.x] = h[threadIdx.x];
}

// ---------------------------------------------------------------------------
// Column-sum partials + exclusive scan -> cbase[0..NC], ccur.
// ---------------------------------------------------------------------------
__global__ __launch_bounds__(256) void cscan_k(
    const int* __restrict__ cpart, int* __restrict__ cbase,
    int* __restrict__ ccur, int NC, int nHB)
{
    __shared__ int sc[256];
    const int t = threadIdx.x;
    int v = 0;
    for (int b = 0; b < nHB; ++b) v += cpart[b * 256 + t];
    sc[t] = v;
    __syncthreads();
    for (int off = 1; off < 256; off <<= 1) {
        int add = (t >= off) ? sc[t - off] : 0;
        __syncthreads();
        sc[t] += add;
        __syncthreads();
    }
    const int ex = sc[t] - v;
    if (t < NC) { cbase[t] = ex; ccur[t] = ex; }
    if (t == 255) cbase[NC] = sc[255];
}

// ---------------------------------------------------------------------------
// Coarse binning: per 2048-edge chunk, stage in LDS, reserve runs, write runs.
// Entry pack: (dlow<<24)|(rel<<16)|src.
// ---------------------------------------------------------------------------
__global__ __launch_bounds__(256) void bin_k(
    const int* __restrict__ ei, const int* __restrict__ rel,
    int* __restrict__ ccur, uint32* __restrict__ binned, int nE)
{
    __shared__ uint32        ent[2048];
    __shared__ unsigned char cid[2048];
    __shared__ int lh[256], lb[256], lc[256];

    const int t = threadIdx.x;
    lh[t] = 0;
    __syncthreads();

    const int base = blockIdx.x * 2048;
    #pragma unroll
    for (int i = 0; i < 8; ++i) {
        const int idx = t + i * 256;
        const int e   = base + idx;
        if (e < nE) {
            const int dst = ei[nE + e];
            ent[idx] = ((uint32)(dst & 255) << 24) | ((uint32)rel[e] << 16) | (uint32)ei[e];
            const int c = dst >> 8;
            cid[idx] = (unsigned char)c;
            atomicAdd(&lh[c], 1);
        } else {
            cid[idx] = 255;   // sentinel (NC <= 254 guard in launcher)
        }
    }
    __syncthreads();

    if (lh[t]) lb[t] = atomicAdd(&ccur[t], lh[t]);
    lc[t] = 0;
    __syncthreads();

    #pragma unroll
    for (int i = 0; i < 8; ++i) {
        const int idx = t + i * 256;
        const int c   = cid[idx];
        if (c != 255) {
            const int off = atomicAdd(&lc[c], 1);
            binned[lb[c] + off] = ent[idx];
        }
    }
}

// ---------------------------------------------------------------------------
// Fine sort within one coarse bucket (keyspace 2048 = dlow*8+rel), in LDS.
// sorted[] keeps (rel<<16)|src for flush-on-rel-change aggregation.
// ---------------------------------------------------------------------------
__global__ __launch_bounds__(1024) void fsort_k(
    const uint32* __restrict__ binned, const int* __restrict__ cbase,
    int* __restrict__ start, int* __restrict__ sorted, int NC)
{
    __shared__ int fh[2048], fex[2048], fcur[2048], sc[1024];
    const int c  = blockIdx.x;
    const int t  = threadIdx.x;
    const int n0 = cbase[c];
    const int n1 = cbase[c + 1];

    fh[t] = 0; fh[t + 1024] = 0;
    __syncthreads();

    for (int j = n0 + t; j < n1; j += 1024) {
        const uint32 en = binned[j];
        atomicAdd(&fh[((en >> 24) << 3) | ((en >> 16) & 7)], 1);
    }
    __syncthreads();

    const int a = fh[2 * t], b = fh[2 * t + 1];
    sc[t] = a + b;
    __syncthreads();
    for (int off = 1; off < 1024; off <<= 1) {
        int add = (t >= off) ? sc[t - off] : 0;
        __syncthreads();
        sc[t] += add;
        __syncthreads();
    }
    const int ep = sc[t] - (a + b);
    fex[2 * t] = ep; fex[2 * t + 1] = ep + a;
    __syncthreads();

    fcur[t] = fex[t]; fcur[t + 1024] = fex[t + 1024];
    {
        const int k0 = c << 11;
        start[k0 + t]        = n0 + fex[t];
        start[k0 + t + 1024] = n0 + fex[t + 1024];
    }
    if (c == NC - 1 && t == 0) start[NC << 11] = n1;
    __syncthreads();

    for (int j = n0 + t; j < n1; j += 1024) {
        const uint32 en = binned[j];
        const int fk  = ((en >> 24) << 3) | ((en >> 16) & 7);
        const int off = atomicAdd(&fcur[fk], 1);
        sorted[n0 + off] = (int)(en & 0x7FFFFu);   // (rel<<16)|src
    }
}

// ---------------------------------------------------------------------------
// Fused aggregate + GEMM. Block = 16 nodes.
// Phase 1: 8 half-waves aggregate 2 nodes each (flat flush-on-rel-change
//   loop, 4-unrolled) into an LDS A-tile [16 rows][256 uints], XOR-swizzled
//   (uint idx ^= (row&7)<<2) so phase-2 column reads are bank-conflict-free.
// Phase 2: wave w computes col-tile w: 16 x mfma_f32_16x16x32_bf16 with
//   A-frags from LDS (ds_read_b128) and B-frags from L2-hot Bfrag.
// C/D layout per m89: col=lane&15, row=(lane>>4)*4+reg.
// ---------------------------------------------------------------------------
#define AGG_FLUSH()                                                          \
    {                                                                        \
        const int widx = (row * 256 + (prev * 2 + (l32 >> 4)) * 16 +         \
                          (l32 & 15)) ^ ((row & 7) << 2);                    \
        als[widx] = packbf(a0, a1);                                          \
    }

#define AGG_PROCESS(eu, uu)                                                  \
    {                                                                        \
        const int r_ = (int)((eu) >> 16);                                    \
        if (r_ != prev) {                                                    \
            if (prev >= 0) AGG_FLUSH();                                      \
            a0 = 0.f; a1 = 0.f;                                              \
            prev = r_;                                                       \
        }                                                                    \
        a0 += bflo(uu); a1 += bfhi(uu);                                      \
    }

__global__ __launch_bounds__(256) void aggemm_k(
    const uint32* __restrict__ xbf, const int* __restrict__ start,
    const int* __restrict__ sorted, const uint32* __restrict__ Bfrag,
    float* __restrict__ out, int nN)
{
    __shared__ uint32 als[NPB * 256];   // 16 KB

    const int t      = threadIdx.x;
    const int hw     = t >> 5;          // half-wave 0..7
    const int l32    = t & 31;
    const int n_base = blockIdx.x * NPB;

    // ---- phase 1: aggregation ----
    #pragma unroll 1
    for (int p = 0; p < 2; ++p) {
        const int row = hw * 2 + p;          // 0..15
        const int n   = n_base + row;

        // zero this node's A-row (covers empty rels and tail rows)
        #pragma unroll
        for (int z = 0; z < 8; ++z)
            als[(row * 256 + z * 32 + l32) ^ ((row & 7) << 2)] = 0u;

        if (n < nN) {
            const int kb = n * NREL;
            const int b0 = start[kb];
            const int b8 = start[kb + 8];

            int   prev = -1;
            float a0 = 0.f, a1 = 0.f;

            int j = b0;
            for (; j + 4 <= b8; j += 4) {
                const uint32 e0 = (uint32)sorted[j];
                const uint32 e1 = (uint32)sorted[j + 1];
                const uint32 e2 = (uint32)sorted[j + 2];
                const uint32 e3 = (uint32)sorted[j + 3];
                const uint32 u0 = xbf[(size_t)(e0 & 0xFFFFu) * 32 + l32];
                const uint32 u1 = xbf[(size_t)(e1 & 0xFFFFu) * 32 + l32];
                const uint32 u2 = xbf[(size_t)(e2 & 0xFFFFu) * 32 + l32];
                const uint32 u3 = xbf[(size_t)(e3 & 0xFFFFu) * 32 + l32];
                AGG_PROCESS(e0, u0);
                AGG_PROCESS(e1, u1);
                AGG_PROCESS(e2, u2);
                AGG_PROCESS(e3, u3);
            }
            for (; j < b8; ++j) {
                const uint32 e = (uint32)sorted[j];
                const uint32 u = xbf[(size_t)(e & 0xFFFFu) * 32 + l32];
                AGG_PROCESS(e, u);
            }
            if (prev >= 0) AGG_FLUSH();
        }
    }
    __syncthreads();

    // ---- phase 2: MFMA ----
    const int lane = t & 63;
    const int w    = t >> 6;            // col tile 0..3
    const int rl   = lane & 15;
    const int kq   = lane >> 4;

    f32x4 acc = (f32x4){0.f, 0.f, 0.f, 0.f};
    const uint32* bp = Bfrag + (size_t)lane * 4;

    #pragma unroll
    for (int ks = 0; ks < 16; ++ks) {
        const int aidx = (rl * 256 + ks * 16 + kq * 4) ^ ((rl & 7) << 2);
        U4 ua, ub;
        ua.u = *(const uint4*)(als + aidx);
        ub.u = *(const uint4*)(bp + (size_t)(ks * 4 + w) * 256);
        acc = __builtin_amdgcn_mfma_f32_16x16x32_bf16(ua.v, ub.v, acc, 0, 0, 0);
    }

    #pragma unroll
    for (int reg = 0; reg < 4; ++reg) {
        const int row = kq * 4 + reg;
        const int n   = n_base + row;
        if (n < nN)
            out[(size_t)n * 64 + w * 16 + rl] = acc[reg];
    }
}

// ---------------------------------------------------------------------------
// Fallback: per-edge direct with atomics.
// ---------------------------------------------------------------------------
__global__ __launch_bounds__(256) void rgcn_direct_kernel(
    const float* __restrict__ x, const float* __restrict__ W,
    const int* __restrict__ ei, const int* __restrict__ rel,
    float* __restrict__ out, int nE, int nWaves)
{
    const int w    = (int)((blockIdx.x * 256u + threadIdx.x) >> 6);
    const int lane = threadIdx.x & 63;

    for (int e = w; e < nE; e += nWaves) {
        const int src = ei[e];
        const int dst = ei[nE + e];
        const int r   = rel[e];
        const float* xrow = x + (size_t)src * CH;
        const float* wcol = W + ((size_t)r << 12) + lane;
        float acc = 0.f;
        #pragma unroll
        for (int i = 0; i < CH; ++i) acc += xrow[i] * wcol[i * CH];
        atomicAdd(out + (size_t)dst * CH + lane, acc);
    }
}

static inline size_t align256(size_t v) { return (v + 255) & ~(size_t)255; }

extern "C" void kernel_launch(void* const* d_in, const int* in_sizes, int n_in,
                              void* d_out, int out_size, void* d_ws, size_t ws_size,
                              hipStream_t stream) {
    const float* x   = (const float*)d_in[0];
    const float* W   = (const float*)d_in[1];
    const int*   ei  = (const int*)d_in[2];
    const int*   rel = (const int*)d_in[3];
    float*       out = (float*)d_out;

    const int nN  = in_sizes[0] / CH;   // 50000
    const int nE  = in_sizes[3];        // 1000000
    const int NC  = (nN + 255) >> 8;    // 196 coarse buckets
    const int nHB = 256;                // chist blocks

    // Workspace layout
    const size_t sz_xbf    = align256((size_t)nN * 32 * sizeof(uint32));        // 6.4 MB
    const size_t sz_start  = align256(((size_t)NC * 2048 + 2) * sizeof(int));   // 1.6 MB
    const size_t sz_binned = align256((size_t)nE * sizeof(uint32));             // 4 MB
    const size_t sz_sorted = align256((size_t)nE * sizeof(int));                // 4 MB
    const size_t sz_bfrag  = align256((size_t)16384 * sizeof(uint32));          // 64 KB
    const size_t sz_cpart  = align256((size_t)nHB * 256 * sizeof(int));         // 256 KB
    const size_t sz_cbase  = align256(257 * sizeof(int));
    const size_t sz_ccur   = align256(256 * sizeof(int));
    const size_t need = sz_xbf + sz_start + sz_binned + sz_sorted +
                        sz_bfrag + sz_cpart + sz_cbase + sz_ccur;

    if (ws_size >= need && nN <= 65024 && NC <= 254) {
        char* p = (char*)d_ws;
        uint32* xbf    = (uint32*)p;  p += sz_xbf;
        int*    start  = (int*)p;     p += sz_start;
        uint32* binned = (uint32*)p;  p += sz_binned;
        int*    sorted = (int*)p;     p += sz_sorted;
        uint32* Bfrag  = (uint32*)p;  p += sz_bfrag;
        int*    cpart  = (int*)p;     p += sz_cpart;
        int*    cbase  = (int*)p;     p += sz_cbase;
        int*    ccur   = (int*)p;

        const int n2 = nN * 32;
        prep_k<<<16 + (n2 + 255) / 256, 256, 0, stream>>>(x, xbf, W, Bfrag, n2);

        chist_k<<<nHB, 256, 0, stream>>>(ei, cpart, nE, nHB * 256);
        cscan_k<<<1, 256, 0, stream>>>(cpart, cbase, ccur, NC, nHB);
        bin_k<<<(nE + 2047) / 2048, 256, 0, stream>>>(ei, rel, ccur, binned, nE);
        fsort_k<<<NC, 1024, 0, stream>>>(binned, cbase, start, sorted, NC);

        aggemm_k<<<(nN + NPB - 1) / NPB, 256, 0, stream>>>(
            xbf, start, sorted, Bfrag, out, nN);
    } else {
        hipMemsetAsync(out, 0, (size_t)out_size * sizeof(float), stream);
        const int blocks = 2048;
        const int nWaves = blocks * (256 / 64);
        rgcn_direct_kernel<<<blocks, 256, 0, stream>>>(x, W, ei, rel, out, nE, nWaves);
    }
}